// Round 13
// baseline (227.812 us; speedup 1.0000x reference)
//
#include <hip/hip_runtime.h>
#include <hip/hip_bf16.h>
#include <cstdint>
#include <cstddef>

#define NROWS 16384
#define DDIM  256
#define SPLITS 16                 // 64 row-blocks x 16 col-splits = 1024 blocks = 4/CU
#define NTILES 256                // 16384 cols / 64

typedef __attribute__((ext_vector_type(4))) float f32x4;
typedef __attribute__((ext_vector_type(4))) float fl4;
typedef __attribute__((ext_vector_type(4))) int   i32x4;
typedef __attribute__((ext_vector_type(8))) int   i32x8;

constexpr float SCALE_EXP2 = 20.609929155556627f; // log2(e)/0.07 folded into qn
constexpr float LN2F       = 0.69314718055994531f;
constexpr float INV_T      = 14.285714285714286f;

__device__ inline void gload_lds16(const void* g, void* l) {
  __builtin_amdgcn_global_load_lds(
      (const __attribute__((address_space(1))) void*)g,
      (__attribute__((address_space(3))) void*)l, 16, 0, 0);
}

// ---- kernel 1: one wave per row i: normalize q_i,k_i -> fp8 (q side pre-scaled
// by log2(e)/T), fp32 diag_i, zero rowsum + counters. No LDS, no barriers.
__global__ __launch_bounds__(256) void norm_kernel(
    const float* __restrict__ q, const float* __restrict__ k,
    unsigned char* __restrict__ qn, unsigned char* __restrict__ kn,
    float* __restrict__ diag, float* __restrict__ rowsum,
    int* __restrict__ cnt, int* __restrict__ done)
{
  const int wave = threadIdx.x >> 6, lane = threadIdx.x & 63;
  const int row = blockIdx.x * 4 + wave;
  const size_t off = (size_t)row * DDIM + lane * 4;

  fl4 vq = *(const fl4*)(q + off);
  fl4 vk = *(const fl4*)(k + off);
  float ssq = vq.x * vq.x + vq.y * vq.y + vq.z * vq.z + vq.w * vq.w;
  float ssk = vk.x * vk.x + vk.y * vk.y + vk.z * vk.z + vk.w * vk.w;
  float dot = vq.x * vk.x + vq.y * vk.y + vq.z * vk.z + vq.w * vk.w;
#pragma unroll
  for (int m = 1; m < 64; m <<= 1) {
    ssq += __shfl_xor(ssq, m, 64);
    ssk += __shfl_xor(ssk, m, 64);
    dot += __shfl_xor(dot, m, 64);
  }
  float rq = 1.0f / fmaxf(sqrtf(ssq), 1e-12f);
  float rk = 1.0f / fmaxf(sqrtf(ssk), 1e-12f);

  float sq = rq * SCALE_EXP2;   // fold exp2 scale into q side
  int pq = __builtin_amdgcn_cvt_pk_fp8_f32(vq.x * sq, vq.y * sq, 0, false);
  pq     = __builtin_amdgcn_cvt_pk_fp8_f32(vq.z * sq, vq.w * sq, pq, true);
  *(int*)(qn + off) = pq;
  int pk = __builtin_amdgcn_cvt_pk_fp8_f32(vk.x * rk, vk.y * rk, 0, false);
  pk     = __builtin_amdgcn_cvt_pk_fp8_f32(vk.z * rk, vk.w * rk, pk, true);
  *(int*)(kn + off) = pk;

  if (lane == 0) {
    diag[row]   = dot * rq * rk * INV_T;
    rowsum[row] = 0.0f;
    if ((row & 255) == 0) cnt[row >> 8] = 0;
    if (row == 0) done[0] = 0;
  }
}

// ---- kernel 2: R9-proven lse body + fused final reduction via counter tree.
// grid 1024 = 64 row-blocks x 16 splits -> 4 blocks/CU = 4 waves/SIMD.
// Double-buffered LDS staging (R9): prefetch tile t+1 after the barrier;
// explicit s_waitcnt(0) before __syncthreads() because the compiler does NOT
// drain LDS-DMA (vmcnt) at s_barrier (R6 NaN post-mortem).
// Tail (R10-proven protocol, fixed aggregation): 16 adds per cnt[rb] line,
// completer reduces its 256 rows, 64 adds on `done`, last block writes out.
// R10's mistake — 16384 adds on ONE line — cost 590 µs (~36 ns each).
// __launch_bounds__(256) ONLY — any min-waves arg splits the unified file and
// spills the A-hoard (R4/R5: 133MB-1GB scratch traffic).
__global__ __launch_bounds__(256) void lse_kernel(
    const unsigned char* __restrict__ qn, const unsigned char* __restrict__ kn,
    float* __restrict__ rowsum, const float* __restrict__ diag,
    int* __restrict__ cnt, int* __restrict__ done,
    float* __restrict__ partial, float* __restrict__ out)
{
  __shared__ __attribute__((aligned(16))) unsigned char Bs[2][64 * DDIM]; // 2 x 16 KB

  const int tid  = threadIdx.x;
  const int wave = tid >> 6, lane = tid & 63;
  const int l15  = lane & 15, quad = lane >> 4;
  const int split = blockIdx.x % SPLITS;
  const int rb    = blockIdx.x / SPLITS;
  const int wrow  = rb * 256 + wave * 64;
  const int t0 = (split * NTILES) / SPLITS;
  const int t1 = ((split + 1) * NTILES) / SPLITS;

  // Staging addresses (i-invariant): chunk L = i*256+tid -> row n = i*16+Ln,
  // slot jj = tid&15 holds global chunk j = jj ^ (n&15) = Ljj ^ Ln.
  const int Ln = tid >> 4, Ljj = tid & 15;
  const int Lj = Ljj ^ Ln;
  const size_t src_off = (size_t)Ln * DDIM + (size_t)Lj * 16;

  // Compute-loop LDS offsets: n&15 == l15 (loop-invariant) -> constants.
  const int o00 = ((quad * 2    ) ^ l15) * 16;
  const int o01 = ((quad * 2 + 1) ^ l15) * 16;
  const int o10 = ((quad * 2 + 8) ^ l15) * 16;
  const int o11 = ((quad * 2 + 9) ^ l15) * 16;

  // A fragments: 4 subtiles x 2 K-steps(128) x 32B/lane = 64 VGPRs.
  // Layout (16x16x128 f8f6f4): m = lane&15, k = quad*32 + j.
  i32x8 A[4][2];
#pragma unroll
  for (int s = 0; s < 4; ++s) {
    const unsigned char* ap = qn + (size_t)(wrow + s * 16 + l15) * DDIM + quad * 32;
#pragma unroll
    for (int ks = 0; ks < 2; ++ks)
      A[s][ks] = *(const i32x8*)(ap + ks * 128);
  }

  float sums[4][4];
#pragma unroll
  for (int s = 0; s < 4; ++s)
#pragma unroll
    for (int r = 0; r < 4; ++r) sums[s][r] = 0.0f;

  // prefetch first tile into buffer 0
  {
    const unsigned char* kbase = kn + (size_t)t0 * 64 * DDIM + src_off;
#pragma unroll
    for (int i = 0; i < 4; ++i)
      gload_lds16(kbase + i * 4096, (void*)(Bs[0] + tid * 16 + i * 4096));
  }

  for (int ct = t0; ct < t1; ++ct) {
    const int cur = (ct - t0) & 1;
    __builtin_amdgcn_s_waitcnt(0);  // drain buf[cur]'s LDS-DMA (compiler won't)
    __syncthreads();                // + all waves done reading buf[cur^1]
    if (ct + 1 < t1) {
      const unsigned char* kbase = kn + (size_t)(ct + 1) * 64 * DDIM + src_off;
#pragma unroll
      for (int i = 0; i < 4; ++i)
        gload_lds16(kbase + i * 4096, (void*)(Bs[cur ^ 1] + tid * 16 + i * 4096));
    }

    const unsigned char* brow = Bs[cur] + l15 * DDIM;
#pragma unroll
    for (int cs = 0; cs < 4; ++cs, brow += 16 * DDIM) {
      f32x4 acc0 = {0.f, 0.f, 0.f, 0.f};
      f32x4 acc1 = {0.f, 0.f, 0.f, 0.f};
      f32x4 acc2 = {0.f, 0.f, 0.f, 0.f};
      f32x4 acc3 = {0.f, 0.f, 0.f, 0.f};
#pragma unroll
      for (int ks = 0; ks < 2; ++ks) {
        i32x4 lo = *(const i32x4*)(brow + (ks ? o10 : o00));
        i32x4 hi = *(const i32x4*)(brow + (ks ? o11 : o01));
        i32x8 b = {lo.x, lo.y, lo.z, lo.w, hi.x, hi.y, hi.z, hi.w};
        acc0 = __builtin_amdgcn_mfma_scale_f32_16x16x128_f8f6f4(A[0][ks], b, acc0, 0, 0, 0, 127, 0, 127);
        acc1 = __builtin_amdgcn_mfma_scale_f32_16x16x128_f8f6f4(A[1][ks], b, acc1, 0, 0, 0, 127, 0, 127);
        acc2 = __builtin_amdgcn_mfma_scale_f32_16x16x128_f8f6f4(A[2][ks], b, acc2, 0, 0, 0, 127, 0, 127);
        acc3 = __builtin_amdgcn_mfma_scale_f32_16x16x128_f8f6f4(A[3][ks], b, acc3, 0, 0, 0, 127, 0, 127);
      }
      // C/D: col = lane&15, row = quad*4 + r. qn pre-scaled -> exp2 directly.
#pragma unroll
      for (int r = 0; r < 4; ++r) {
        sums[0][r] += __builtin_amdgcn_exp2f(acc0[r]);
        sums[1][r] += __builtin_amdgcn_exp2f(acc1[r]);
        sums[2][r] += __builtin_amdgcn_exp2f(acc2[r]);
        sums[3][r] += __builtin_amdgcn_exp2f(acc3[r]);
      }
    }
  }

  // Row accumulation into rowsum (16 atomics per wave, spread addresses).
#pragma unroll
  for (int s = 0; s < 4; ++s)
#pragma unroll
    for (int r = 0; r < 4; ++r) {
      float v = sums[s][r];
      v += __shfl_xor(v, 1, 64);
      v += __shfl_xor(v, 2, 64);
      v += __shfl_xor(v, 4, 64);
      v += __shfl_xor(v, 8, 64);
      if (l15 == 0) atomicAdd(&rowsum[wrow + s * 16 + quad * 4 + r], v);
    }

  // ---- fused final: counter tree (release/acquire via __threadfence) ----
  __threadfence();                       // release rowsum adds
  __shared__ int sflag;
  if (tid == 0) {
    int o = atomicAdd(&cnt[rb], 1);
    sflag = (o == SPLITS - 1) ? 1 : 0;   // this block completes row-block rb
  }
  __syncthreads();
  if (sflag) {
    __threadfence();                     // acquire other splits' rowsum adds
    int row = rb * 256 + tid;
    float tot = atomicAdd(&rowsum[row], 0.0f);   // atomic read of final total
    float c = __builtin_amdgcn_logf(tot) * LN2F - diag[row];
#pragma unroll
    for (int m = 1; m < 64; m <<= 1) c += __shfl_xor(c, m, 64);
    float* red = (float*)Bs;
    if (lane == 0) red[wave] = c;
    __syncthreads();
    if (tid == 0) {
      partial[rb] = red[0] + red[1] + red[2] + red[3];
      __threadfence();                   // release partial[rb]
      int o2 = atomicAdd(done, 1);
      sflag = (o2 == 63) ? 2 : 0;        // last row-block finisher
    }
    __syncthreads();
    if (sflag == 2) {
      __threadfence();                   // acquire all partials
      if (tid < 64) {
        float v = atomicAdd(&partial[tid], 0.0f);  // atomic read
#pragma unroll
        for (int m = 1; m < 64; m <<= 1) v += __shfl_xor(v, m, 64);
        if (tid == 0) out[0] = v * (1.0f / NROWS);
      }
    }
  }
}

extern "C" void kernel_launch(void* const* d_in, const int* in_sizes, int n_in,
                              void* d_out, int out_size, void* d_ws, size_t ws_size,
                              hipStream_t stream)
{
  const float* q = (const float*)d_in[0];
  const float* k = (const float*)d_in[1];
  float* out = (float*)d_out;

  char* ws = (char*)d_ws;
  unsigned char* qn = (unsigned char*)ws;                    // 4 MB
  unsigned char* kn = (unsigned char*)(ws + (4u << 20));     // 4 MB
  float* diag    = (float*)(ws + (8u << 20));                // 64 KB
  float* rowsum  = (float*)(ws + (8u << 20) + (64u << 10));  // 64 KB
  int*   cnt     = (int*)  (ws + (8u << 20) + (128u << 10)); // 256 B
  int*   done    = cnt + 64;                                 // 4 B
  float* partial = (float*)(cnt + 128);                      // 256 B

  norm_kernel <<<NROWS / 4, 256, 0, stream>>>(q, k, qn, kn, diag, rowsum, cnt, done);
  lse_kernel  <<<(NROWS / 256) * SPLITS, 256, 0, stream>>>(qn, kn, rowsum, diag,
                                                           cnt, done, partial, out);
}

// Round 14
// 147.125 us; speedup vs baseline: 1.5484x; 1.5484x over previous
//
#include <hip/hip_runtime.h>
#include <hip/hip_bf16.h>
#include <cstdint>
#include <cstddef>

#define NROWS 16384
#define DDIM  256
#define SPLITS 16                 // 64 row-blocks x 16 col-splits = 1024 blocks = 4/CU
#define TPS   64                  // 16-col tiles per split (1024 cols / 16)

typedef __attribute__((ext_vector_type(4))) float f32x4;
typedef __attribute__((ext_vector_type(4))) float fl4;
typedef __attribute__((ext_vector_type(4))) int   i32x4;
typedef __attribute__((ext_vector_type(8))) int   i32x8;

constexpr float SCALE_EXP2 = 20.609929155556627f; // log2(e)/0.07 folded into qn
constexpr float LN2F       = 0.69314718055994531f;
constexpr float INV_T      = 14.285714285714286f;

__device__ inline void gload_lds16(const void* g, void* l) {
  __builtin_amdgcn_global_load_lds(
      (const __attribute__((address_space(1))) void*)g,
      (__attribute__((address_space(3))) void*)l, 16, 0, 0);
}

// ---- kernel 1 (R9-proven): one wave per row i: normalize q_i,k_i -> fp8
// (q side pre-scaled by log2(e)/T), fp32 diag_i, zero rowsum.
__global__ __launch_bounds__(256) void norm_kernel(
    const float* __restrict__ q, const float* __restrict__ k,
    unsigned char* __restrict__ qn, unsigned char* __restrict__ kn,
    float* __restrict__ diag, float* __restrict__ rowsum,
    float* __restrict__ out)
{
  const int wave = threadIdx.x >> 6, lane = threadIdx.x & 63;
  const int row = blockIdx.x * 4 + wave;
  const size_t off = (size_t)row * DDIM + lane * 4;

  fl4 vq = *(const fl4*)(q + off);
  fl4 vk = *(const fl4*)(k + off);
  float ssq = vq.x * vq.x + vq.y * vq.y + vq.z * vq.z + vq.w * vq.w;
  float ssk = vk.x * vk.x + vk.y * vk.y + vk.z * vk.z + vk.w * vk.w;
  float dot = vq.x * vk.x + vq.y * vk.y + vq.z * vk.z + vq.w * vk.w;
#pragma unroll
  for (int m = 1; m < 64; m <<= 1) {
    ssq += __shfl_xor(ssq, m, 64);
    ssk += __shfl_xor(ssk, m, 64);
    dot += __shfl_xor(dot, m, 64);
  }
  float rq = 1.0f / fmaxf(sqrtf(ssq), 1e-12f);
  float rk = 1.0f / fmaxf(sqrtf(ssk), 1e-12f);

  float sq = rq * SCALE_EXP2;   // fold exp2 scale into q side
  int pq = __builtin_amdgcn_cvt_pk_fp8_f32(vq.x * sq, vq.y * sq, 0, false);
  pq     = __builtin_amdgcn_cvt_pk_fp8_f32(vq.z * sq, vq.w * sq, pq, true);
  *(int*)(qn + off) = pq;
  int pk = __builtin_amdgcn_cvt_pk_fp8_f32(vk.x * rk, vk.y * rk, 0, false);
  pk     = __builtin_amdgcn_cvt_pk_fp8_f32(vk.z * rk, vk.w * rk, pk, true);
  *(int*)(kn + off) = pk;

  if (lane == 0) {
    diag[row]   = dot * rq * rk * INV_T;
    rowsum[row] = 0.0f;
    if (row == 0) out[0] = 0.0f;
  }
}

// ---- kernel 2: BARRIER-FREE lse. Each wave owns a private 8 KB LDS region
// (2 x 4 KB buffers) and stages its own 16-col B-tile via global_load_lds,
// 2 tiles deep, gated by explicit `s_waitcnt vmcnt(N)` inline asm (memory
// clobber = compiler cannot hoist the dependent ds_reads above it — the R6
// hazard). No __syncthreads anywhere: R9's barrier phase-locked all resident
// waves into simultaneous MFMA bursts then simultaneous exp2 bursts, defeating
// cross-wave pipe overlap (78 us vs ~38 us pipe floor). Waves now de-phase
// freely; a tile's loads get ~2 compute phases (~1.6k cyc) before use.
// L2 read traffic x4 vs shared staging (~1 GB total ≈ 30 us at L2 BW, hidden).
// grid 1024 = 64 row-blocks x 16 splits = 4 blocks/CU; LDS 32 KB/block.
// __launch_bounds__(256) ONLY — any min-waves arg splits the unified file and
// spills the A-hoard (R4/R5: 133MB-1GB scratch traffic).
__global__ __launch_bounds__(256) void lse_kernel(
    const unsigned char* __restrict__ qn, const unsigned char* __restrict__ kn,
    float* __restrict__ rowsum)
{
  __shared__ __attribute__((aligned(16))) unsigned char Bs[32768]; // 4 waves x 2 x 4 KB

  const int tid  = threadIdx.x;
  const int wave = tid >> 6, lane = tid & 63;
  const int l15  = lane & 15, quad = lane >> 4;
  const int split = blockIdx.x % SPLITS;
  const int rb    = blockIdx.x / SPLITS;
  const int wrow  = rb * 256 + wave * 64;
  const int col_base = split * (TPS * 16);

  unsigned char* wb = Bs + wave * 8192;   // this wave's private region

  // Stage one 16-col tile (16 cols x 256 B = 4 KB) into buffer `buf`.
  // Chunk L = i*64 + lane -> col n = i*4 + quad, slot jj = l15 holds global
  // chunk j = jj ^ n (bank-swizzle; measured 0 conflicts in R9's equivalent).
  // LDS dest = uniform base + lane*16 (m104 rule).
  auto stage = [&](int ct, int buf) {
    const unsigned char* kbase = kn + (size_t)(col_base + ct * 16) * DDIM;
    unsigned char* dst = wb + buf * 4096 + lane * 16;
#pragma unroll
    for (int i = 0; i < 4; ++i) {
      const int n = i * 4 + quad;
      gload_lds16(kbase + (size_t)n * DDIM + ((l15 ^ n) * 16), dst + i * 1024);
    }
  };

  // Compute-side swizzled chunk offsets (col n = l15 -> n&15 == l15, constant):
  // ks0 needs chunks 2q,2q+1 of col l15; ks1 needs 8+2q,8+2q+1.
  const int o00 = ((quad * 2    ) ^ l15) * 16;
  const int o01 = ((quad * 2 + 1) ^ l15) * 16;
  const int o10 = ((quad * 2 + 8) ^ l15) * 16;
  const int o11 = ((quad * 2 + 9) ^ l15) * 16;

  // A fragments: 4 subtiles x 2 K-steps(128) x 32B/lane = 64 VGPRs.
  // Layout (16x16x128 f8f6f4): m = lane&15, k = quad*32 + j.
  i32x8 A[4][2];
#pragma unroll
  for (int s = 0; s < 4; ++s) {
    const unsigned char* ap = qn + (size_t)(wrow + s * 16 + l15) * DDIM + quad * 32;
#pragma unroll
    for (int ks = 0; ks < 2; ++ks)
      A[s][ks] = *(const i32x8*)(ap + ks * 128);
  }

  float sums[4][4];
#pragma unroll
  for (int s = 0; s < 4; ++s)
#pragma unroll
    for (int r = 0; r < 4; ++r) sums[s][r] = 0.0f;

  stage(0, 0);
  stage(1, 1);

  for (int ct = 0; ct < TPS; ++ct) {
    const int cur = ct & 1;
    // Gate on tile ct's 4 loads: steady state has 8 outstanding (ct, ct+1);
    // vmcnt(4) drains the oldest 4. Last iteration has only 4 -> vmcnt(0).
    if (ct + 1 < TPS) { asm volatile("s_waitcnt vmcnt(4)" ::: "memory"); }
    else              { asm volatile("s_waitcnt vmcnt(0)" ::: "memory"); }

    const unsigned char* brow = wb + cur * 4096 + l15 * 256;
    f32x4 acc0 = {0.f, 0.f, 0.f, 0.f};
    f32x4 acc1 = {0.f, 0.f, 0.f, 0.f};
    f32x4 acc2 = {0.f, 0.f, 0.f, 0.f};
    f32x4 acc3 = {0.f, 0.f, 0.f, 0.f};
    {
      i32x4 lo = *(const i32x4*)(brow + o00);
      i32x4 hi = *(const i32x4*)(brow + o01);
      i32x8 b = {lo.x, lo.y, lo.z, lo.w, hi.x, hi.y, hi.z, hi.w};
      acc0 = __builtin_amdgcn_mfma_scale_f32_16x16x128_f8f6f4(A[0][0], b, acc0, 0, 0, 0, 127, 0, 127);
      acc1 = __builtin_amdgcn_mfma_scale_f32_16x16x128_f8f6f4(A[1][0], b, acc1, 0, 0, 0, 127, 0, 127);
      acc2 = __builtin_amdgcn_mfma_scale_f32_16x16x128_f8f6f4(A[2][0], b, acc2, 0, 0, 0, 127, 0, 127);
      acc3 = __builtin_amdgcn_mfma_scale_f32_16x16x128_f8f6f4(A[3][0], b, acc3, 0, 0, 0, 127, 0, 127);
    }
    {
      i32x4 lo = *(const i32x4*)(brow + o10);
      i32x4 hi = *(const i32x4*)(brow + o11);
      i32x8 b = {lo.x, lo.y, lo.z, lo.w, hi.x, hi.y, hi.z, hi.w};
      acc0 = __builtin_amdgcn_mfma_scale_f32_16x16x128_f8f6f4(A[0][1], b, acc0, 0, 0, 0, 127, 0, 127);
      acc1 = __builtin_amdgcn_mfma_scale_f32_16x16x128_f8f6f4(A[1][1], b, acc1, 0, 0, 0, 127, 0, 127);
      acc2 = __builtin_amdgcn_mfma_scale_f32_16x16x128_f8f6f4(A[2][1], b, acc2, 0, 0, 0, 127, 0, 127);
      acc3 = __builtin_amdgcn_mfma_scale_f32_16x16x128_f8f6f4(A[3][1], b, acc3, 0, 0, 0, 127, 0, 127);
    }
    // C/D: col = lane&15, row = quad*4 + r. qn pre-scaled -> exp2 directly.
#pragma unroll
    for (int r = 0; r < 4; ++r) {
      sums[0][r] += __builtin_amdgcn_exp2f(acc0[r]);
      sums[1][r] += __builtin_amdgcn_exp2f(acc1[r]);
      sums[2][r] += __builtin_amdgcn_exp2f(acc2[r]);
      sums[3][r] += __builtin_amdgcn_exp2f(acc3[r]);
    }

    // Refill the buffer we just consumed (its ds_reads are retired: the
    // compiler's lgkm waits precede the MFMAs, which precede this issue).
    if (ct + 2 < TPS) stage(ct + 2, cur);
  }

#pragma unroll
  for (int s = 0; s < 4; ++s)
#pragma unroll
    for (int r = 0; r < 4; ++r) {
      float v = sums[s][r];
      v += __shfl_xor(v, 1, 64);
      v += __shfl_xor(v, 2, 64);
      v += __shfl_xor(v, 4, 64);
      v += __shfl_xor(v, 8, 64);
      if (l15 == 0) atomicAdd(&rowsum[wrow + s * 16 + quad * 4 + r], v);
    }
}

// ---- kernel 3 (R9-proven): out = mean(ln(rowsum) - diag). Block-reduced:
// 64 single-address atomics total (R10: 16384 hot-line atomics cost ~590 us).
__global__ void final_kernel(const float* __restrict__ rowsum,
                             const float* __restrict__ diag,
                             float* __restrict__ out)
{
  int row = blockIdx.x * 256 + threadIdx.x;
  float c = __builtin_amdgcn_logf(rowsum[row]) * LN2F - diag[row];
#pragma unroll
  for (int m = 1; m < 64; m <<= 1) c += __shfl_xor(c, m, 64);
  __shared__ float red[4];
  int wave = threadIdx.x >> 6, lane = threadIdx.x & 63;
  if (lane == 0) red[wave] = c;
  __syncthreads();
  if (threadIdx.x == 0) {
    float s = red[0] + red[1] + red[2] + red[3];
    atomicAdd(out, s * (1.0f / NROWS));
  }
}

extern "C" void kernel_launch(void* const* d_in, const int* in_sizes, int n_in,
                              void* d_out, int out_size, void* d_ws, size_t ws_size,
                              hipStream_t stream)
{
  const float* q = (const float*)d_in[0];
  const float* k = (const float*)d_in[1];
  float* out = (float*)d_out;

  char* ws = (char*)d_ws;
  unsigned char* qn = (unsigned char*)ws;                    // 4 MB
  unsigned char* kn = (unsigned char*)(ws + (4u << 20));     // 4 MB
  float* diag   = (float*)(ws + (8u << 20));                 // 64 KB
  float* rowsum = (float*)(ws + (8u << 20) + (64u << 10));   // 64 KB

  norm_kernel <<<NROWS / 4, 256, 0, stream>>>(q, k, qn, kn, diag, rowsum, out);
  lse_kernel  <<<(NROWS / 256) * SPLITS, 256, 0, stream>>>(qn, kn, rowsum);
  final_kernel<<<NROWS / 256, 256, 0, stream>>>(rowsum, diag, out);
}